// Round 3
// baseline (154.797 us; speedup 1.0000x reference)
//
#include <hip/hip_runtime.h>
#include <stdint.h>

// Problem constants
static constexpr int B_ROWS = 8192;
static constexpr int C_COLS = 1024;
static constexpr uint32_t HALF_N = 4194304u;  // B*C/2
static constexpr int NPAIR = B_ROWS / 2;      // 4096 row-pairs

__device__ __forceinline__ uint32_t rotl32(uint32_t x, int d) {
  return (x << d) | (x >> (32 - d));
}

// JAX Threefry-2x32 with key (0, 42), 20 rounds. (verified bit-exact R0/R1)
__device__ __forceinline__ void threefry2x32_k42(uint32_t& x0, uint32_t& x1) {
  const uint32_t ks0 = 0u;
  const uint32_t ks1 = 42u;
  const uint32_t ks2 = 0u ^ 42u ^ 0x1BD11BDAu;
  x0 += ks0; x1 += ks1;
#define TF_R(r) { x0 += x1; x1 = rotl32(x1, (r)); x1 ^= x0; }
  TF_R(13) TF_R(15) TF_R(26) TF_R(6)
  x0 += ks1; x1 += ks2 + 1u;
  TF_R(17) TF_R(29) TF_R(16) TF_R(24)
  x0 += ks2; x1 += ks0 + 2u;
  TF_R(13) TF_R(15) TF_R(26) TF_R(6)
  x0 += ks0; x1 += ks1 + 3u;
  TF_R(17) TF_R(29) TF_R(16) TF_R(24)
  x0 += ks1; x1 += ks2 + 4u;
  TF_R(13) TF_R(15) TF_R(26) TF_R(6)
  x0 += ks2; x1 += ks0 + 5u;
#undef TF_R
}

// One WAVE per row-pair (rows p and p+4096 share threefry counter pairs).
// 64-thread blocks: no barriers anywhere (single-wave LDS is instruction-
// ordered), waves drift freely -> latency hiding across 16 blocks/CU.
__global__ __launch_bounds__(64) void attr_loss_main(
    const float* __restrict__ scores, const int* __restrict__ attrs,
    float* __restrict__ out) {
  __shared__ int hist[2][256];

  const int lane = threadIdx.x;
  const int pair = blockIdx.x;  // 0..4095
  const size_t base0 = (size_t)pair * C_COLS;
  const size_t base1 = (size_t)(pair + NPAIR) * C_COLS;

  // ---- issue ALL global loads first; latency overlaps threefry compute ----
  float4 sv[2][4];
  int4 av[2][4];
#pragma unroll
  for (int i = 0; i < 4; ++i) {
    const int col = i * 256 + lane * 4;
    sv[0][i] = *reinterpret_cast<const float4*>(scores + base0 + col);
    sv[1][i] = *reinterpret_cast<const float4*>(scores + base1 + col);
    av[0][i] = *reinterpret_cast<const int4*>(attrs + base0 + col);
    av[1][i] = *reinterpret_cast<const int4*>(attrs + base1 + col);
  }

  // ---- clear both wave-private histograms (no barrier: same-wave order) ----
  *reinterpret_cast<int4*>(&hist[0][lane * 4]) = make_int4(0, 0, 0, 0);
  *reinterpret_cast<int4*>(&hist[1][lane * 4]) = make_int4(0, 0, 0, 0);

  // ---- threefry keys for both rows (pure VALU, overlaps load latency) ----
  uint32_t key[2][16];
#pragma unroll
  for (int i = 0; i < 4; ++i) {
#pragma unroll
    for (int j = 0; j < 4; ++j) {
      const int col = i * 256 + lane * 4 + j;
      uint32_t x0 = (uint32_t)(pair * C_COLS + col);
      uint32_t x1 = x0 + HALF_N;
      threefry2x32_k42(x0, x1);
      const uint32_t cb = (uint32_t)col >> 1;
      key[0][i * 4 + j] = (x0 & 0xFFFFFE00u) | cb;
      key[1][i * 4 + j] = (x1 & 0xFFFFFE00u) | cb;
    }
  }

  // ---- zero-attr masks ----
  uint32_t zm[2] = {0u, 0u};
#pragma unroll
  for (int r = 0; r < 2; ++r) {
#pragma unroll
    for (int i = 0; i < 4; ++i) {
      zm[r] |= (av[r][i].x == 0 ? 1u : 0u) << (i * 4 + 0);
      zm[r] |= (av[r][i].y == 0 ? 1u : 0u) << (i * 4 + 1);
      zm[r] |= (av[r][i].z == 0 ? 1u : 0u) << (i * 4 + 2);
      zm[r] |= (av[r][i].w == 0 ? 1u : 0u) << (i * 4 + 3);
    }
  }

  // ---- fill both histograms (top byte of key, zero-attr only) ----
#pragma unroll
  for (int r = 0; r < 2; ++r) {
#pragma unroll
    for (int e = 0; e < 16; ++e) {
      if ((zm[r] >> e) & 1u) atomicAdd(&hist[r][key[r][e] >> 24], 1);
    }
  }

  // ---- per-row radix-1 select: threshold key T[r] at rank k-1 ----
  int kk[2];
  uint32_t T[2];
#pragma unroll
  for (int r = 0; r < 2; ++r) {
    const int4 hv = *reinterpret_cast<const int4*>(&hist[r][lane * 4]);
    const int s0 = hv.x, s1 = s0 + hv.y, s2 = s1 + hv.z, s3 = s2 + hv.w;
    int incl = s3;
#pragma unroll
    for (int d = 1; d < 64; d <<= 1) {
      const int o = __shfl_up(incl, d, 64);
      if (lane >= d) incl += o;
    }
    const int excl = incl - s3;
    const int n_zero = __shfl(incl, 63, 64);
    const int k = (int)rintf(0.95f * (float)n_zero);
    kk[r] = k;
    T[r] = 0u;
    if (k > 0) {
      const int target = k - 1;
      int myb = -1, myt = 0;
      const int ce0 = excl, ce1 = excl + s0, ce2 = excl + s1, ce3 = excl + s2;
      if (hv.x > 0 && ce0 <= target && target < ce0 + hv.x) { myb = lane * 4 + 0; myt = target - ce0; }
      if (hv.y > 0 && ce1 <= target && target < ce1 + hv.y) { myb = lane * 4 + 1; myt = target - ce1; }
      if (hv.z > 0 && ce2 <= target && target < ce2 + hv.z) { myb = lane * 4 + 2; myt = target - ce2; }
      if (hv.w > 0 && ce3 <= target && target < ce3 + hv.w) { myb = lane * 4 + 3; myt = target - ce3; }
      const unsigned long long bm = __ballot(myb >= 0);
      const int src = __ffsll(bm) - 1;
      const uint32_t bucket = (uint32_t)__shfl(myb, src, 64);
      int tt = __shfl(myt, src, 64);

      // exact k-th smallest within bucket (expected ~2 candidates, uniform loop)
      uint32_t lowbar = 0u;
      while (true) {
        uint32_t mm = 0xFFFFFFFFu;
#pragma unroll
        for (int e = 0; e < 16; ++e) {
          const uint32_t kv = key[r][e];
          if (((zm[r] >> e) & 1u) && (kv >> 24) == bucket && kv >= lowbar)
            mm = mm < kv ? mm : kv;
        }
#pragma unroll
        for (int d = 32; d >= 1; d >>= 1) {
          const uint32_t o = (uint32_t)__shfl_xor((int)mm, d, 64);
          mm = mm < o ? mm : o;
        }
        int c = 0;
#pragma unroll
        for (int e = 0; e < 16; ++e)
          c += (((zm[r] >> e) & 1u) && key[r][e] == mm) ? 1 : 0;
#pragma unroll
        for (int d = 32; d >= 1; d >>= 1) c += __shfl_xor(c, d, 64);
        if (tt < c) { T[r] = mm; break; }
        tt -= c;
        lowbar = mm + 1u;
      }
    }
  }

  // ---- masked loss, both rows ----
  float lsum = 0.f;
#pragma unroll
  for (int r = 0; r < 2; ++r) {
#pragma unroll
    for (int i = 0; i < 4; ++i) {
      const float ss[4] = {sv[r][i].x, sv[r][i].y, sv[r][i].z, sv[r][i].w};
#pragma unroll
      for (int j = 0; j < 4; ++j) {
        const int e = i * 4 + j;
        const float s = ss[j];
        // log1p(exp(-|s|)): arg in (1,2], fast log absolutely accurate here
        const float cmn = __logf(1.f + __expf(-fabsf(s)));
        if ((zm[r] >> e) & 1u) {
          if (kk[r] <= 0 || key[r][e] > T[r]) lsum += fminf(-s, 0.f) - cmn;
        } else {
          lsum += fminf(s, 0.f) - cmn;
        }
      }
    }
  }

  // ---- wave reduce -> one float atomic per pair (scale 2^-23 is exact) ----
#pragma unroll
  for (int d = 32; d >= 1; d >>= 1) lsum += __shfl_xor(lsum, d, 64);
  if (lane == 0) {
    atomicAdd(out, lsum * (-1.0f / 8388608.0f));
  }
}

extern "C" void kernel_launch(void* const* d_in, const int* in_sizes, int n_in,
                              void* d_out, int out_size, void* d_ws, size_t ws_size,
                              hipStream_t stream) {
  const float* scores = (const float*)d_in[0];
  const int* attrs = (const int*)d_in[1];
  float* out = (float*)d_out;

  hipMemsetAsync(d_out, 0, sizeof(float), stream);
  attr_loss_main<<<NPAIR, 64, 0, stream>>>(scores, attrs, out);
}

// Round 4
// 105.987 us; speedup vs baseline: 1.4605x; 1.4605x over previous
//
#include <hip/hip_runtime.h>
#include <stdint.h>

// Problem constants
static constexpr int B_ROWS = 8192;
static constexpr int C_COLS = 1024;
static constexpr uint32_t HALF_N = 4194304u;  // B*C/2
static constexpr int NPAIR = B_ROWS / 2;      // 4096 row-pairs

__device__ __forceinline__ uint32_t rotl32(uint32_t x, int d) {
  return (x << d) | (x >> (32 - d));
}

// JAX Threefry-2x32 with key (0, 42), 20 rounds. (verified bit-exact R0-R3)
__device__ __forceinline__ void threefry2x32_k42(uint32_t& x0, uint32_t& x1) {
  const uint32_t ks0 = 0u;
  const uint32_t ks1 = 42u;
  const uint32_t ks2 = 0u ^ 42u ^ 0x1BD11BDAu;
  x0 += ks0; x1 += ks1;
#define TF_R(r) { x0 += x1; x1 = rotl32(x1, (r)); x1 ^= x0; }
  TF_R(13) TF_R(15) TF_R(26) TF_R(6)
  x0 += ks1; x1 += ks2 + 1u;
  TF_R(17) TF_R(29) TF_R(16) TF_R(24)
  x0 += ks2; x1 += ks0 + 2u;
  TF_R(13) TF_R(15) TF_R(26) TF_R(6)
  x0 += ks0; x1 += ks1 + 3u;
  TF_R(17) TF_R(29) TF_R(16) TF_R(24)
  x0 += ks1; x1 += ks2 + 4u;
  TF_R(13) TF_R(15) TF_R(26) TF_R(6)
  x0 += ks2; x1 += ks0 + 5u;
#undef TF_R
}

// Block = 128 threads = 2 waves, handles one row-pair (rows p, p+4096).
// Wave w computes threefry for cols [w*512, w*512+512) -> BOTH rows' keys
// for those cols; keeps its own row's half, exchanges the other half via
// LDS (one barrier). Then per-wave private histogram select + loss.
// No global atomics: per-wave partial to d_ws.
__global__ __launch_bounds__(128) void attr_loss_main(
    const float* __restrict__ scores, const int* __restrict__ attrs,
    float* __restrict__ partials) {
  __shared__ int hist[2][256];
  __shared__ uint32_t xbuf[2][512];  // xbuf[w] written by wave w, read by 1-w

  const int t = threadIdx.x;
  const int lane = t & 63;
  const int w = t >> 6;           // 0 or 1
  const int pair = blockIdx.x;    // 0..4095
  const int myrow = pair + w * NPAIR;   // wave w owns this row
  const int selfc0 = w * 512 + lane * 8;        // cols of self-computed elems
  const int othc0 = (1 - w) * 512 + lane * 8;   // cols of exchanged elems

  // ---- attrs for my row (both segments), issued first ----
  int4 a0 = *reinterpret_cast<const int4*>(attrs + (size_t)myrow * C_COLS + selfc0);
  int4 a1 = *reinterpret_cast<const int4*>(attrs + (size_t)myrow * C_COLS + selfc0 + 4);
  int4 a2 = *reinterpret_cast<const int4*>(attrs + (size_t)myrow * C_COLS + othc0);
  int4 a3 = *reinterpret_cast<const int4*>(attrs + (size_t)myrow * C_COLS + othc0 + 4);

  // ---- clear my histogram (wave-private; ordered before my LDS atomics) ----
  *reinterpret_cast<int4*>(&hist[w][lane * 4]) = make_int4(0, 0, 0, 0);

  // ---- threefry: 8 counters -> keys for row p (x0) and row p+4096 (x1) ----
  uint32_t key[16];
#pragma unroll
  for (int j = 0; j < 8; ++j) {
    const int col = selfc0 + j;
    uint32_t x0 = (uint32_t)(pair * C_COLS + col);
    uint32_t x1 = x0 + HALF_N;
    threefry2x32_k42(x0, x1);
    const uint32_t cb = (uint32_t)col >> 1;
    const uint32_t k0 = (x0 & 0xFFFFFE00u) | cb;  // row p
    const uint32_t k1 = (x1 & 0xFFFFFE00u) | cb;  // row p+4096
    key[j] = w ? k1 : k0;                         // keep my row's key
    xbuf[w][j * 64 + lane] = w ? k0 : k1;         // send the other row's key
  }
  __syncthreads();
#pragma unroll
  for (int j = 0; j < 8; ++j) {
    key[8 + j] = xbuf[1 - w][j * 64 + lane];      // my row, other col half
  }

  // ---- zero-attr mask for my 16 elements ----
  uint32_t zm = 0u;
  zm |= (a0.x == 0 ? 1u : 0u) << 0;  zm |= (a0.y == 0 ? 1u : 0u) << 1;
  zm |= (a0.z == 0 ? 1u : 0u) << 2;  zm |= (a0.w == 0 ? 1u : 0u) << 3;
  zm |= (a1.x == 0 ? 1u : 0u) << 4;  zm |= (a1.y == 0 ? 1u : 0u) << 5;
  zm |= (a1.z == 0 ? 1u : 0u) << 6;  zm |= (a1.w == 0 ? 1u : 0u) << 7;
  zm |= (a2.x == 0 ? 1u : 0u) << 8;  zm |= (a2.y == 0 ? 1u : 0u) << 9;
  zm |= (a2.z == 0 ? 1u : 0u) << 10; zm |= (a2.w == 0 ? 1u : 0u) << 11;
  zm |= (a3.x == 0 ? 1u : 0u) << 12; zm |= (a3.y == 0 ? 1u : 0u) << 13;
  zm |= (a3.z == 0 ? 1u : 0u) << 14; zm |= (a3.w == 0 ? 1u : 0u) << 15;

  // ---- fill my histogram (top byte of key, zero-attr only) ----
#pragma unroll
  for (int e = 0; e < 16; ++e) {
    if ((zm >> e) & 1u) atomicAdd(&hist[w][key[e] >> 24], 1);
  }

  // ---- scores for my row (issued now; latency overlaps the scan below) ----
  const float4 s0 = *reinterpret_cast<const float4*>(scores + (size_t)myrow * C_COLS + selfc0);
  const float4 s1 = *reinterpret_cast<const float4*>(scores + (size_t)myrow * C_COLS + selfc0 + 4);
  const float4 s2 = *reinterpret_cast<const float4*>(scores + (size_t)myrow * C_COLS + othc0);
  const float4 s3 = *reinterpret_cast<const float4*>(scores + (size_t)myrow * C_COLS + othc0 + 4);

  // ---- radix-1 select: threshold key T at rank k-1 among zero-attr keys ----
  const int4 hv = *reinterpret_cast<const int4*>(&hist[w][lane * 4]);
  const int c0 = hv.x, c1 = c0 + hv.y, c2 = c1 + hv.z, c3 = c2 + hv.w;
  int incl = c3;
#pragma unroll
  for (int d = 1; d < 64; d <<= 1) {
    const int o = __shfl_up(incl, d, 64);
    if (lane >= d) incl += o;
  }
  const int excl = incl - c3;
  const int n_zero = __shfl(incl, 63, 64);
  const int k = (int)rintf(0.95f * (float)n_zero);

  uint32_t T = 0u;
  if (k > 0) {
    const int target = k - 1;
    int myb = -1, myt = 0;
    const int ce0 = excl, ce1 = excl + c0, ce2 = excl + c1, ce3 = excl + c2;
    if (hv.x > 0 && ce0 <= target && target < ce0 + hv.x) { myb = lane * 4 + 0; myt = target - ce0; }
    if (hv.y > 0 && ce1 <= target && target < ce1 + hv.y) { myb = lane * 4 + 1; myt = target - ce1; }
    if (hv.z > 0 && ce2 <= target && target < ce2 + hv.z) { myb = lane * 4 + 2; myt = target - ce2; }
    if (hv.w > 0 && ce3 <= target && target < ce3 + hv.w) { myb = lane * 4 + 3; myt = target - ce3; }
    const unsigned long long bm = __ballot(myb >= 0);
    const int src = __ffsll(bm) - 1;
    const uint32_t bucket = (uint32_t)__shfl(myb, src, 64);
    int tt = __shfl(myt, src, 64);

    // exact k-th smallest within bucket (expected ~2 candidates)
    uint32_t lowbar = 0u;
    while (true) {
      uint32_t mm = 0xFFFFFFFFu;
#pragma unroll
      for (int e = 0; e < 16; ++e) {
        const uint32_t kv = key[e];
        if (((zm >> e) & 1u) && (kv >> 24) == bucket && kv >= lowbar)
          mm = mm < kv ? mm : kv;
      }
#pragma unroll
      for (int d = 32; d >= 1; d >>= 1) {
        const uint32_t o = (uint32_t)__shfl_xor((int)mm, d, 64);
        mm = mm < o ? mm : o;
      }
      int c = 0;
#pragma unroll
      for (int e = 0; e < 16; ++e)
        c += (((zm >> e) & 1u) && key[e] == mm) ? 1 : 0;
#pragma unroll
      for (int d = 32; d >= 1; d >>= 1) c += __shfl_xor(c, d, 64);
      if (tt < c) { T = mm; break; }
      tt -= c;
      lowbar = mm + 1u;
    }
  }

  // ---- masked loss for my row's 16 elements ----
  float lsum = 0.f;
  const float ss[16] = {s0.x, s0.y, s0.z, s0.w, s1.x, s1.y, s1.z, s1.w,
                        s2.x, s2.y, s2.z, s2.w, s3.x, s3.y, s3.z, s3.w};
#pragma unroll
  for (int e = 0; e < 16; ++e) {
    const float s = ss[e];
    // log1p(exp(-|s|)): arg in (1,2], fast log absolutely accurate here
    const float cmn = __logf(1.f + __expf(-fabsf(s)));
    if ((zm >> e) & 1u) {
      if (k <= 0 || key[e] > T) lsum += fminf(-s, 0.f) - cmn;
    } else {
      lsum += fminf(s, 0.f) - cmn;
    }
  }

  // ---- wave reduce -> per-wave partial (no atomics) ----
#pragma unroll
  for (int d = 32; d >= 1; d >>= 1) lsum += __shfl_xor(lsum, d, 64);
  if (lane == 0) partials[blockIdx.x * 2 + w] = lsum;
}

__global__ __launch_bounds__(256) void finalize_kernel(
    const float* __restrict__ partials, float* __restrict__ out) {
  __shared__ double wred[4];
  const int t = threadIdx.x;
  const int lane = t & 63;
  const int w = t >> 6;
  double s = 0.0;
#pragma unroll
  for (int i = 0; i < 32; ++i) s += (double)partials[t + i * 256];
#pragma unroll
  for (int d = 32; d >= 1; d >>= 1) s += __shfl_xor(s, d, 64);
  if (lane == 0) wred[w] = s;
  __syncthreads();
  if (t == 0) {
    const double tot = wred[0] + wred[1] + wred[2] + wred[3];
    out[0] = (float)(-tot / ((double)B_ROWS * (double)C_COLS));
  }
}

extern "C" void kernel_launch(void* const* d_in, const int* in_sizes, int n_in,
                              void* d_out, int out_size, void* d_ws, size_t ws_size,
                              hipStream_t stream) {
  const float* scores = (const float*)d_in[0];
  const int* attrs = (const int*)d_in[1];
  float* out = (float*)d_out;
  float* partials = (float*)d_ws;  // 8192 floats = 32 KB scratch

  attr_loss_main<<<NPAIR, 128, 0, stream>>>(scores, attrs, partials);
  finalize_kernel<<<1, 256, 0, stream>>>(partials, out);
}

// Round 5
// 105.222 us; speedup vs baseline: 1.4711x; 1.0073x over previous
//
#include <hip/hip_runtime.h>
#include <stdint.h>

// Problem constants
static constexpr int B_ROWS = 8192;
static constexpr int C_COLS = 1024;
static constexpr uint32_t HALF_N = 4194304u;  // B*C/2
static constexpr int NPAIR = B_ROWS / 2;      // 4096 row-pairs

__device__ __forceinline__ uint32_t rotl32(uint32_t x, int d) {
  return (x << d) | (x >> (32 - d));
}

// JAX Threefry-2x32 with key (0, 42), 20 rounds. (verified bit-exact R0-R4)
__device__ __forceinline__ void threefry2x32_k42(uint32_t& x0, uint32_t& x1) {
  const uint32_t ks0 = 0u;
  const uint32_t ks1 = 42u;
  const uint32_t ks2 = 0u ^ 42u ^ 0x1BD11BDAu;
  x0 += ks0; x1 += ks1;
#define TF_R(r) { x0 += x1; x1 = rotl32(x1, (r)); x1 ^= x0; }
  TF_R(13) TF_R(15) TF_R(26) TF_R(6)
  x0 += ks1; x1 += ks2 + 1u;
  TF_R(17) TF_R(29) TF_R(16) TF_R(24)
  x0 += ks2; x1 += ks0 + 2u;
  TF_R(13) TF_R(15) TF_R(26) TF_R(6)
  x0 += ks0; x1 += ks1 + 3u;
  TF_R(17) TF_R(29) TF_R(16) TF_R(24)
  x0 += ks1; x1 += ks2 + 4u;
  TF_R(13) TF_R(15) TF_R(26) TF_R(6)
  x0 += ks2; x1 += ks0 + 5u;
#undef TF_R
}

// ---- DPP wave64 primitives (no DS pipe; ~2-4 cyc per step) ----
// Inclusive add-scan: row_shr 1/2/4/8 then row_bcast15 (rows 1,3) and
// row_bcast31 (rows 2,3). Invalid/masked lanes contribute `old`=identity.
__device__ __forceinline__ int wave_iscan_add(int x) {
  x += __builtin_amdgcn_update_dpp(0, x, 0x111, 0xf, 0xf, false);
  x += __builtin_amdgcn_update_dpp(0, x, 0x112, 0xf, 0xf, false);
  x += __builtin_amdgcn_update_dpp(0, x, 0x114, 0xf, 0xf, false);
  x += __builtin_amdgcn_update_dpp(0, x, 0x118, 0xf, 0xf, false);
  x += __builtin_amdgcn_update_dpp(0, x, 0x142, 0xa, 0xf, false);
  x += __builtin_amdgcn_update_dpp(0, x, 0x143, 0xc, 0xf, false);
  return x;  // lane63 holds the wave total
}

__device__ __forceinline__ uint32_t wave_min_u32(uint32_t x) {
  uint32_t t;
#define MSTEP(ctrl, rmask)                                                   \
  t = (uint32_t)__builtin_amdgcn_update_dpp(-1, (int)x, ctrl, rmask, 0xf, false); \
  x = (t < x) ? t : x;
  MSTEP(0x111, 0xf) MSTEP(0x112, 0xf) MSTEP(0x114, 0xf) MSTEP(0x118, 0xf)
  MSTEP(0x142, 0xa) MSTEP(0x143, 0xc)
#undef MSTEP
  return x;  // lane63 holds the wave min
}

__device__ __forceinline__ int wave_max_i32(int x) {  // all inputs >= -1
  int t;
#define XSTEP(ctrl, rmask)                                                   \
  t = __builtin_amdgcn_update_dpp(-1, x, ctrl, rmask, 0xf, false);           \
  x = (t > x) ? t : x;
  XSTEP(0x111, 0xf) XSTEP(0x112, 0xf) XSTEP(0x114, 0xf) XSTEP(0x118, 0xf)
  XSTEP(0x142, 0xa) XSTEP(0x143, 0xc)
#undef XSTEP
  return x;  // lane63 holds the wave max
}

__device__ __forceinline__ float wave_fadd(float x) {
#define FSTEP(ctrl, rmask)                                                   \
  x += __int_as_float(                                                       \
      __builtin_amdgcn_update_dpp(0, __float_as_int(x), ctrl, rmask, 0xf, false));
  FSTEP(0x111, 0xf) FSTEP(0x112, 0xf) FSTEP(0x114, 0xf) FSTEP(0x118, 0xf)
  FSTEP(0x142, 0xa) FSTEP(0x143, 0xc)
#undef FSTEP
  return x;  // lane63 holds the wave sum
}

// Block = 128 threads = 2 waves, one row-pair (rows p, p+4096). Wave w
// computes threefry for cols [w*512, w*512+512) -> both rows' keys, keeps
// its own row's half, exchanges the other via LDS (one barrier). All
// cross-lane work is DPP (VALU); LDS is used only for the 256-bin
// histogram (16 atomics + 1 read per wave) and the key exchange.
__global__ __launch_bounds__(128) void attr_loss_main(
    const float* __restrict__ scores, const int* __restrict__ attrs,
    float* __restrict__ partials) {
  __shared__ int hist[2][256];
  __shared__ uint32_t xbuf[2][512];

  const int t = threadIdx.x;
  const int lane = t & 63;
  const int w = t >> 6;
  const int pair = blockIdx.x;
  const int myrow = pair + w * NPAIR;
  const int selfc0 = w * 512 + lane * 8;
  const int othc0 = (1 - w) * 512 + lane * 8;

  // attrs first (needed for zm before histogram)
  const int4 a0 = *reinterpret_cast<const int4*>(attrs + (size_t)myrow * C_COLS + selfc0);
  const int4 a1 = *reinterpret_cast<const int4*>(attrs + (size_t)myrow * C_COLS + selfc0 + 4);
  const int4 a2 = *reinterpret_cast<const int4*>(attrs + (size_t)myrow * C_COLS + othc0);
  const int4 a3 = *reinterpret_cast<const int4*>(attrs + (size_t)myrow * C_COLS + othc0 + 4);

  // clear my wave-private histogram (same-wave LDS is program-ordered)
  *reinterpret_cast<int4*>(&hist[w][lane * 4]) = make_int4(0, 0, 0, 0);

  // threefry: 8 counter pairs -> keys for both rows of the pair
  uint32_t key[16];
#pragma unroll
  for (int j = 0; j < 8; ++j) {
    const int col = selfc0 + j;
    uint32_t x0 = (uint32_t)(pair * C_COLS + col);
    uint32_t x1 = x0 + HALF_N;
    threefry2x32_k42(x0, x1);
    const uint32_t cb = (uint32_t)col >> 1;
    const uint32_t k0 = (x0 & 0xFFFFFE00u) | cb;
    const uint32_t k1 = (x1 & 0xFFFFFE00u) | cb;
    key[j] = w ? k1 : k0;
    xbuf[w][j * 64 + lane] = w ? k0 : k1;
  }
  __syncthreads();
#pragma unroll
  for (int j = 0; j < 8; ++j) key[8 + j] = xbuf[1 - w][j * 64 + lane];

  // zero-attr mask
  uint32_t zm = 0u;
  zm |= (a0.x == 0 ? 1u : 0u) << 0;  zm |= (a0.y == 0 ? 1u : 0u) << 1;
  zm |= (a0.z == 0 ? 1u : 0u) << 2;  zm |= (a0.w == 0 ? 1u : 0u) << 3;
  zm |= (a1.x == 0 ? 1u : 0u) << 4;  zm |= (a1.y == 0 ? 1u : 0u) << 5;
  zm |= (a1.z == 0 ? 1u : 0u) << 6;  zm |= (a1.w == 0 ? 1u : 0u) << 7;
  zm |= (a2.x == 0 ? 1u : 0u) << 8;  zm |= (a2.y == 0 ? 1u : 0u) << 9;
  zm |= (a2.z == 0 ? 1u : 0u) << 10; zm |= (a2.w == 0 ? 1u : 0u) << 11;
  zm |= (a3.x == 0 ? 1u : 0u) << 12; zm |= (a3.y == 0 ? 1u : 0u) << 13;
  zm |= (a3.z == 0 ? 1u : 0u) << 14; zm |= (a3.w == 0 ? 1u : 0u) << 15;

  // histogram of key top byte over zero-attr elements
#pragma unroll
  for (int e = 0; e < 16; ++e) {
    if ((zm >> e) & 1u) atomicAdd(&hist[w][key[e] >> 24], 1);
  }

  // scores issued now; latency hidden under select
  const float4 s0 = *reinterpret_cast<const float4*>(scores + (size_t)myrow * C_COLS + selfc0);
  const float4 s1 = *reinterpret_cast<const float4*>(scores + (size_t)myrow * C_COLS + selfc0 + 4);
  const float4 s2 = *reinterpret_cast<const float4*>(scores + (size_t)myrow * C_COLS + othc0);
  const float4 s3 = *reinterpret_cast<const float4*>(scores + (size_t)myrow * C_COLS + othc0 + 4);

  // scan histogram, locate rank k-1 bucket
  const int4 hv = *reinterpret_cast<const int4*>(&hist[w][lane * 4]);
  const int c0 = hv.x, c1 = c0 + hv.y, c2 = c1 + hv.z, c3 = c2 + hv.w;
  const int incl = wave_iscan_add(c3);
  const int excl = incl - c3;
  const int n_zero = __builtin_amdgcn_readlane(incl, 63);
  const int k = (int)rintf(0.95f * (float)n_zero);

  uint32_t T = 0u;
  if (k > 0) {
    const int target = k - 1;
    int enc = -1;  // (bucket << 16) | within-bucket-rank, exactly one lane sets it
    const int ce0 = excl, ce1 = excl + c0, ce2 = excl + c1, ce3 = excl + c2;
    if (hv.x > 0 && ce0 <= target && target < ce0 + hv.x) enc = ((lane * 4 + 0) << 16) | (target - ce0);
    if (hv.y > 0 && ce1 <= target && target < ce1 + hv.y) enc = ((lane * 4 + 1) << 16) | (target - ce1);
    if (hv.z > 0 && ce2 <= target && target < ce2 + hv.z) enc = ((lane * 4 + 2) << 16) | (target - ce2);
    if (hv.w > 0 && ce3 <= target && target < ce3 + hv.w) enc = ((lane * 4 + 3) << 16) | (target - ce3);
    const int benc = __builtin_amdgcn_readlane(wave_max_i32(enc), 63);
    const uint32_t bucket = (uint32_t)(benc >> 16);
    int tt = benc & 0xFFFF;

    // in-bucket candidate bitmask (computed once)
    uint32_t inb = 0u;
#pragma unroll
    for (int e = 0; e < 16; ++e) {
      if (((zm >> e) & 1u) && (key[e] >> 24) == bucket) inb |= 1u << e;
    }

    // exact k-th smallest within bucket (expected ~1.5 iterations)
    uint32_t lowbar = 0u;
    while (true) {
      uint32_t mm = 0xFFFFFFFFu;
#pragma unroll
      for (int e = 0; e < 16; ++e) {
        if (((inb >> e) & 1u) && key[e] >= lowbar) mm = mm < key[e] ? mm : key[e];
      }
      const uint32_t gmin = (uint32_t)__builtin_amdgcn_readlane((int)wave_min_u32(mm), 63);
      int c = 0;
#pragma unroll
      for (int e = 0; e < 16; ++e) c += (((inb >> e) & 1u) && key[e] == gmin) ? 1 : 0;
      const int ctot = __builtin_amdgcn_readlane(wave_iscan_add(c), 63);
      if (tt < ctot) { T = gmin; break; }
      tt -= ctot;
      lowbar = gmin + 1u;
    }
  }

  // masked loss
  float lsum = 0.f;
  const float ss[16] = {s0.x, s0.y, s0.z, s0.w, s1.x, s1.y, s1.z, s1.w,
                        s2.x, s2.y, s2.z, s2.w, s3.x, s3.y, s3.z, s3.w};
#pragma unroll
  for (int e = 0; e < 16; ++e) {
    const float s = ss[e];
    // log1p(exp(-|s|)): arg in (1,2], fast log absolutely accurate here
    const float cmn = __logf(1.f + __expf(-fabsf(s)));
    if ((zm >> e) & 1u) {
      if (k <= 0 || key[e] > T) lsum += fminf(-s, 0.f) - cmn;
    } else {
      lsum += fminf(s, 0.f) - cmn;
    }
  }

  // wave reduce (DPP) -> per-wave partial
  lsum = wave_fadd(lsum);
  if (lane == 63) partials[blockIdx.x * 2 + w] = lsum;
}

__global__ __launch_bounds__(256) void finalize_kernel(
    const float* __restrict__ partials, float* __restrict__ out) {
  __shared__ double wred[4];
  const int t = threadIdx.x;
  const int lane = t & 63;
  const int w = t >> 6;
  double s = 0.0;
#pragma unroll
  for (int i = 0; i < 32; ++i) s += (double)partials[t + i * 256];
#pragma unroll
  for (int d = 32; d >= 1; d >>= 1) s += __shfl_xor(s, d, 64);
  if (lane == 0) wred[w] = s;
  __syncthreads();
  if (t == 0) {
    const double tot = wred[0] + wred[1] + wred[2] + wred[3];
    out[0] = (float)(-tot / ((double)B_ROWS * (double)C_COLS));
  }
}

extern "C" void kernel_launch(void* const* d_in, const int* in_sizes, int n_in,
                              void* d_out, int out_size, void* d_ws, size_t ws_size,
                              hipStream_t stream) {
  const float* scores = (const float*)d_in[0];
  const int* attrs = (const int*)d_in[1];
  float* out = (float*)d_out;
  float* partials = (float*)d_ws;  // 8192 floats = 32 KB scratch

  attr_loss_main<<<NPAIR, 128, 0, stream>>>(scores, attrs, partials);
  finalize_kernel<<<1, 256, 0, stream>>>(partials, out);
}